// Round 5
// baseline (76.996 us; speedup 1.0000x reference)
//
#include <hip/hip_runtime.h>

#define VEC_D   128
#define N_WORDS 100000
#define BATCH   16384
#define CTX     8
#define NS      16
#define NTILES  3125          // N_WORDS / 32
#define NBINS   3328          // NTILES padded to 13*256
#define CAP     256           // bucket capacity; mean fill 84, P(overflow) ~ 1e-50

typedef float f32x4 __attribute__((ext_vector_type(4)));
typedef int   i32x4 __attribute__((ext_vector_type(4)));

// ---------------------------------------------------------------------------
// Zero the per-tile counters (ws is poisoned 0xAA, and we atomicAdd into
// counts each call -> must re-zero every launch; 13*256 == NBINS exactly).
// ---------------------------------------------------------------------------
__global__ __launch_bounds__(256) void zero_kernel(int* __restrict__ counts) {
    counts[blockIdx.x * 256 + threadIdx.x] = 0;
}

// ---------------------------------------------------------------------------
// Phase A: inputs[b] = pm[doc_ids[b]] + sum_c wm[context_ids[b][c]]
// 32 lanes per row (lane r owns d = 4r..4r+3), 8 rows per 256-thread block.
// Also histogram-scatters this block's 128 (b,s) sample pairs into per-tile
// buckets: bin = wid>>5, entry = (p<<5)|(wid&31) with p = b*NS+s (p < 2^18,
// entry < 2^23). Bucket order is atomic-race-dependent but each p is placed
// exactly once and writes a unique out slot -> output deterministic.
// ---------------------------------------------------------------------------
__global__ __launch_bounds__(256, 4) void build_inputs_kernel(
    const int*   __restrict__ doc_ids,
    const int*   __restrict__ context_ids,
    const int*   __restrict__ sample_ids,
    const float* __restrict__ pm,       // [N_DOCS][128]
    const float* __restrict__ wm,       // [N_WORDS][128]
    float*       __restrict__ inputs,   // [BATCH][128]   (ws)
    int*         __restrict__ counts,   // [NBINS]        (ws)
    int*         __restrict__ bucket)   // [NBINS][CAP]   (ws)
{
    const int tid = threadIdx.x;
    const int r   = tid & 31;
    const int b   = blockIdx.x * 8 + (tid >> 5);
    const int d0  = r * 4;

    const int doc = doc_ids[b];
    f32x4 v = *(const f32x4*)&pm[(size_t)doc * VEC_D + d0];

    const i32x4* cid = (const i32x4*)&context_ids[b * CTX];
    #pragma unroll
    for (int g = 0; g < 2; ++g) {              // 2 batches of 4 ctx gathers in flight
        const i32x4 c4 = cid[g];
        f32x4 w[4];
        #pragma unroll
        for (int k = 0; k < 4; ++k)
            w[k] = *(const f32x4*)&wm[(size_t)c4[k] * VEC_D + d0];
        #pragma unroll
        for (int k = 0; k < 4; ++k)
            v += w[k];
    }
    *(f32x4*)&inputs[(size_t)b * VEC_D + d0] = v;   // coalesced 512B/row

    // histogram-scatter the 128 samples belonging to this block's 8 rows
    if (tid < 8 * NS) {
        const int p   = blockIdx.x * (8 * NS) + tid;  // flat b*NS+s
        const int w   = sample_ids[p];
        const int bin = w >> 5;
        const int pos = atomicAdd(&counts[bin], 1);
        if (pos < CAP)
            bucket[bin * CAP + pos] = (p << 5) | (w & 31);
    }
}

// ---------------------------------------------------------------------------
// Phase C: one block per 32-word tile. Stage outputs[:, w0..w0+31] into LDS
// transposed (tile[w_local][d]); outputs is read exactly once, nontemporal.
// Staging writes: per (k,q) instruction lanes hit bank (d%32) with 2 lanes/bank
// -> 2-way, free (m136). Dot reads: 32 contiguous f32x4 per group -> ideal.
// Then each 32-lane group processes bucket entries: gather inputs[b] (512B
// rows from the 8MB L2/L3-resident table), dot vs tile column, butterfly
// reduce (masks <=16 stay inside the 32-lane half), lane 0 writes out[p].
// Index check (hand-verified; harness can't catch sample bugs since outputs
// is all-zero): w = t*32 + (e&31); out[b,s] = sum_d inputs[b,d]*outputs[d,w].
// ---------------------------------------------------------------------------
__global__ __launch_bounds__(256, 4) void dot_kernel(
    const float* __restrict__ outputs,  // [128][N_WORDS]
    const float* __restrict__ inputs,   // [BATCH][128]
    const int*   __restrict__ counts,   // [NBINS]
    const int*   __restrict__ bucket,   // [NBINS][CAP]
    float*       __restrict__ out)      // [BATCH][NS]
{
    __shared__ float tile[32][VEC_D];   // [w_local][d], 16 KB
    const int tid = threadIdx.x;
    const int t   = blockIdx.x;
    const int w0  = t * 32;

    const int d    = tid >> 1;          // 0..127
    const int half = tid & 1;           // which 16-word half of the tile
    #pragma unroll
    for (int k = 0; k < 4; ++k) {
        const int wl = half * 16 + k * 4;
        const f32x4 vv = __builtin_nontemporal_load(
            (const f32x4*)&outputs[(size_t)d * N_WORDS + w0 + wl]);
        tile[wl + 0][d] = vv.x;
        tile[wl + 1][d] = vv.y;
        tile[wl + 2][d] = vv.z;
        tile[wl + 3][d] = vv.w;
    }
    __syncthreads();

    const int cnt = min(counts[t], CAP);
    const int grp = tid >> 5;           // 8 pair-groups per block
    const int r   = tid & 31;
    for (int i = grp; i < cnt; i += 8) {
        const int e  = bucket[t * CAP + i];   // uniform across the group
        const int p  = e >> 5;
        const int wl = e & 31;
        const f32x4 iv = *(const f32x4*)&inputs[(size_t)(p >> 4) * VEC_D + r * 4];
        const f32x4 ov = *(const f32x4*)&tile[wl][r * 4];
        float a = iv.x * ov.x + iv.y * ov.y + iv.z * ov.z + iv.w * ov.w;
        #pragma unroll
        for (int m = 16; m; m >>= 1)
            a += __shfl_xor(a, m, 64);
        if (r == 0)
            out[p] = a;
    }
}

extern "C" void kernel_launch(void* const* d_in, const int* in_sizes, int n_in,
                              void* d_out, int out_size, void* d_ws, size_t ws_size,
                              hipStream_t stream) {
    const int*   doc_ids     = (const int*)d_in[0];
    const int*   context_ids = (const int*)d_in[1];
    const int*   sample_ids  = (const int*)d_in[2];
    const float* pm          = (const float*)d_in[3];
    const float* wm          = (const float*)d_in[4];
    const float* outputs     = (const float*)d_in[5];
    float*       out         = (float*)d_out;

    // ws layout: [inputs 8MB][counts 13KB][bucket 3.4MB]  (~11.5MB, ws is ~268MB)
    float* inputs = (float*)d_ws;
    int*   counts = (int*)((char*)d_ws + (size_t)BATCH * VEC_D * sizeof(float));
    int*   bucket = counts + NBINS;

    zero_kernel<<<NBINS / 256, 256, 0, stream>>>(counts);
    build_inputs_kernel<<<BATCH / 8, 256, 0, stream>>>(
        doc_ids, context_ids, sample_ids, pm, wm, inputs, counts, bucket);
    dot_kernel<<<NTILES, 256, 0, stream>>>(outputs, inputs, counts, bucket, out);
}